// Round 1
// baseline (47.012 us; speedup 1.0000x reference)
//
#include <hip/hip_runtime.h>

typedef float f32x4 __attribute__((ext_vector_type(4)));
typedef _Float16 f16x8 __attribute__((ext_vector_type(8)));

static __device__ __forceinline__ unsigned pk2(float a, float b) {
    unsigned short ua = __builtin_bit_cast(unsigned short, (_Float16)a);
    unsigned short ub = __builtin_bit_cast(unsigned short, (_Float16)b);
    return (unsigned)ua | ((unsigned)ub << 16);
}

#define MFMA16(A, B, C) __builtin_amdgcn_mfma_f32_16x16x32_f16((A), (B), (C), 0, 0, 0)

// qkv: [2][2048][3][16][64] f32; layout: [128][8] i32; out: [2][2048][16][64] f32
// Workgroup (b,h,j): Q rows [256j, 256j+256), K-blocks where layout says active.
// 4 waves x 64 q-rows each. S^T = mfma(K, Q^T); O^T = mfma(V^T, P^T).
__global__ __launch_bounds__(256) void fba_fwd(const float* __restrict__ qkv,
                                               const int* __restrict__ layout,
                                               float* __restrict__ out) {
    __shared__ unsigned short Klds[128 * 64];   // [key][d] f16, byte ^= (key&7)<<4
    __shared__ unsigned short Vtlds[64 * 128];  // [d][key] f16, byte ^= ((d^(d>>3))&7)<<4
    __shared__ unsigned short Plds[4][64 * 40]; // per-wave P[q][k], rows padded to 40 f16 (80 B)
    __shared__ int activeF[8];

    const int bid = blockIdx.x;
    const int vid = (bid & 7) * 32 + (bid >> 3); // XCD-aware swizzle (256 wgs, 8 XCDs)
    const int b = vid >> 7;
    const int h = (vid >> 3) & 15;
    const int j = vid & 7;

    const int tid = threadIdx.x;
    const int w = tid >> 6;
    const int lane = tid & 63;
    const int l15 = lane & 15;
    const int g = lane >> 4;

    if (tid < 8) {
        int a = 0;
        for (int r = 0; r < 16; ++r) a |= layout[(16 * j + r) * 8 + tid];
        activeF[tid] = a;
    }

    const size_t bbase = (size_t)b * 2048 * 3072;
    const int qbase = 256 * j + 64 * w;

    // Q fragments (B-operand of S^T): lane l -> Q[s = qbase+16nt+l15][d = kk*32+8g+e]
    f16x8 qf[4][2];
    #pragma unroll
    for (int nt = 0; nt < 4; ++nt) {
        const float* qp = qkv + bbase + (size_t)(qbase + 16 * nt + l15) * 3072 + h * 64;
        #pragma unroll
        for (int kk = 0; kk < 2; ++kk) {
            const float* p0 = qp + kk * 32 + 8 * g;
            float4 x = *(const float4*)p0;
            float4 y = *(const float4*)(p0 + 4);
            f16x8 q8;
            q8[0] = (_Float16)x.x; q8[1] = (_Float16)x.y; q8[2] = (_Float16)x.z; q8[3] = (_Float16)x.w;
            q8[4] = (_Float16)y.x; q8[5] = (_Float16)y.y; q8[6] = (_Float16)y.z; q8[7] = (_Float16)y.w;
            qf[nt][kk] = q8;
        }
    }

    f32x4 acc[4][4]; // [dtile][qtile]: O^T[d=16*mt2+4g+r][q=16*nt+l15]
    #pragma unroll
    for (int i0 = 0; i0 < 4; ++i0)
        #pragma unroll
        for (int i1 = 0; i1 < 4; ++i1)
            acc[i0][i1] = (f32x4){0.f, 0.f, 0.f, 0.f};
    float mrow[4] = {-INFINITY, -INFINITY, -INFINITY, -INFINITY};
    float lrow[4] = {0.f, 0.f, 0.f, 0.f};

    __syncthreads();

    for (int kb = 0; kb < 8; ++kb) {
        if (!activeF[kb]) continue;
        for (int half = 0; half < 2; ++half) {
            __syncthreads();
            const size_t sbase = bbase + (size_t)(kb * 256 + half * 128) * 3072;
            // ---- stage K half-block: [key 0..127][d 0..63] f16, swizzled
            const float* kp0 = qkv + sbase + (16 + h) * 64;
            #pragma unroll 2
            for (int p = 0; p < 8; ++p) {
                int i = p * 256 + tid;
                int key = i >> 4, dc = i & 15;
                float4 v4 = *(const float4*)(kp0 + (size_t)key * 3072 + dc * 4);
                unsigned w0 = pk2(v4.x, v4.y), w1 = pk2(v4.z, v4.w);
                int off = (key * 128 + dc * 8) ^ ((key & 7) << 4);
                *(uint2*)((char*)Klds + off) = make_uint2(w0, w1);
            }
            // ---- stage V^T half-block: [d 0..63][key 0..127] f16, packed key-pairs
            const float* vp0 = qkv + sbase + (32 + h) * 64;
            #pragma unroll 2
            for (int p = 0; p < 4; ++p) {
                int i = p * 256 + tid;
                int kp = i >> 4, dc = i & 15; // keys 2kp,2kp+1; d = 4dc..4dc+3
                const float* r0 = vp0 + (size_t)(2 * kp) * 3072 + dc * 4;
                float4 va = *(const float4*)r0;
                float4 vb = *(const float4*)(r0 + 3072);
                #pragma unroll
                for (int e = 0; e < 4; ++e) {
                    int d = 4 * dc + e;
                    unsigned u = pk2((&va.x)[e], (&vb.x)[e]);
                    int off = (d * 256 + kp * 4) ^ (((d ^ (d >> 3)) & 7) << 4);
                    *(unsigned*)((char*)Vtlds + off) = u;
                }
            }
            __syncthreads();

            // ---- 4 chunks of 32 keys
            for (int c = 0; c < 4; ++c) {
                f16x8 kf[2][2];
                #pragma unroll
                for (int mt = 0; mt < 2; ++mt)
                    #pragma unroll
                    for (int kk = 0; kk < 2; ++kk) {
                        int key = c * 32 + 16 * mt + l15;
                        int off = (key * 128 + kk * 64 + g * 16) ^ ((key & 7) << 4);
                        kf[mt][kk] = *(const f16x8*)((const char*)Klds + off);
                    }
                f16x8 vf[4];
                #pragma unroll
                for (int mt = 0; mt < 4; ++mt) {
                    int d = 16 * mt + l15;
                    int off = (d * 256 + c * 64 + g * 16) ^ (((d ^ (d >> 3)) & 7) << 4);
                    vf[mt] = *(const f16x8*)((const char*)Vtlds + off);
                }
                #pragma unroll
                for (int nt = 0; nt < 4; ++nt) {
                    // S^T tiles: lane holds S^T[key = c*32 + 16mt + 4g + r][q = 16nt + l15]
                    f32x4 st0 = {0.f, 0.f, 0.f, 0.f};
                    f32x4 st1 = {0.f, 0.f, 0.f, 0.f};
                    st0 = MFMA16(kf[0][0], qf[nt][0], st0);
                    st0 = MFMA16(kf[0][1], qf[nt][1], st0);
                    st1 = MFMA16(kf[1][0], qf[nt][0], st1);
                    st1 = MFMA16(kf[1][1], qf[nt][1], st1);
                    float s0[4], s1[4];
                    float cm = -INFINITY;
                    #pragma unroll
                    for (int r = 0; r < 4; ++r) {
                        s0[r] = st0[r] * 0.125f;
                        s1[r] = st1[r] * 0.125f;
                        cm = fmaxf(cm, fmaxf(s0[r], s1[r]));
                    }
                    cm = fmaxf(cm, __shfl_xor(cm, 16));
                    cm = fmaxf(cm, __shfl_xor(cm, 32));
                    float mnew = fmaxf(mrow[nt], cm);
                    float rs = __expf(mrow[nt] - mnew);
                    mrow[nt] = mnew;
                    float p0[4], p1[4], ps = 0.f;
                    #pragma unroll
                    for (int r = 0; r < 4; ++r) {
                        p0[r] = __expf(s0[r] - mnew);
                        p1[r] = __expf(s1[r] - mnew);
                        ps += p0[r] + p1[r];
                    }
                    ps += __shfl_xor(ps, 16);
                    ps += __shfl_xor(ps, 32);
                    lrow[nt] = lrow[nt] * rs + ps;
                    #pragma unroll
                    for (int mt2 = 0; mt2 < 4; ++mt2) {
                        acc[mt2][nt][0] *= rs; acc[mt2][nt][1] *= rs;
                        acc[mt2][nt][2] *= rs; acc[mt2][nt][3] *= rs;
                    }
                    // P^T regs are 4 contiguous k of P[q][k] -> one b64 write per tile
                    char* pb = (char*)(&Plds[w][0]) + (16 * nt + l15) * 80;
                    *(uint2*)(pb + 8 * g)      = make_uint2(pk2(p0[0], p0[1]), pk2(p0[2], p0[3]));
                    *(uint2*)(pb + 32 + 8 * g) = make_uint2(pk2(p1[0], p1[1]), pk2(p1[2], p1[3]));
                    // B-frag of P^T: row q = 16nt+l15, k = 8g..8g+7 contiguous
                    f16x8 pf = *(const f16x8*)((const char*)(&Plds[w][0]) + (16 * nt + l15) * 80 + 16 * g);
                    #pragma unroll
                    for (int mt2 = 0; mt2 < 4; ++mt2)
                        acc[mt2][nt] = MFMA16(vf[mt2], pf, acc[mt2][nt]);
                }
            }
        }
    }

    // epilogue: O = O^T / l ; lane's 4 regs are contiguous d -> float4 store
    #pragma unroll
    for (int nt = 0; nt < 4; ++nt) {
        float inv = 1.0f / lrow[nt];
        float* op = out + (((size_t)b * 2048 + (qbase + 16 * nt + l15)) * 16 + h) * 64;
        #pragma unroll
        for (int mt2 = 0; mt2 < 4; ++mt2) {
            float4 o;
            o.x = acc[mt2][nt][0] * inv;
            o.y = acc[mt2][nt][1] * inv;
            o.z = acc[mt2][nt][2] * inv;
            o.w = acc[mt2][nt][3] * inv;
            *(float4*)(op + 16 * mt2 + 4 * g) = o;
        }
    }
}

extern "C" void kernel_launch(void* const* d_in, const int* in_sizes, int n_in,
                              void* d_out, int out_size, void* d_ws, size_t ws_size,
                              hipStream_t stream) {
    const float* qkv = (const float*)d_in[0];
    const int* layout = (const int*)d_in[1];
    float* out = (float*)d_out;
    fba_fwd<<<dim3(256), dim3(256), 0, stream>>>(qkv, layout, out);
}

// Round 2
// 34.530 us; speedup vs baseline: 1.3615x; 1.3615x over previous
//
#include <hip/hip_runtime.h>

typedef float f32x4 __attribute__((ext_vector_type(4)));
typedef _Float16 f16x8 __attribute__((ext_vector_type(8)));

static __device__ __forceinline__ unsigned pk2(float a, float b) {
    unsigned short ua = __builtin_bit_cast(unsigned short, (_Float16)a);
    unsigned short ub = __builtin_bit_cast(unsigned short, (_Float16)b);
    return (unsigned)ua | ((unsigned)ub << 16);
}

#define MFMA16(A, B, C) __builtin_amdgcn_mfma_f32_16x16x32_f16((A), (B), (C), 0, 0, 0)

// qkv: [2][2048][3][16][64] f32; layout: [128][8] i32; out: [2][2048][16][64] f32
// Workgroup (b,h,j,qs): Q rows [256j+64qs, +64), K-blocks where layout says active.
// 4 waves x 16 q-rows each. S^T = mfma(K, Q^T); O^T = mfma(V^T, P^T).
// 1024 wgs -> 4 wg/CU (vs round-0's 1 wg/CU) for latency hiding via TLP.
__global__ __launch_bounds__(256, 4) void fba_fwd(const float* __restrict__ qkv,
                                                  const int* __restrict__ layout,
                                                  float* __restrict__ out) {
    __shared__ unsigned short Klds[128 * 64];   // [key][d] f16, byte ^= (key&7)<<4
    __shared__ unsigned short Vtlds[64 * 128];  // [d][key] f16, byte ^= ((d^(d>>3))&7)<<4
    __shared__ unsigned short Plds[4][16 * 40]; // per-wave P[q][k], rows padded to 40 f16 (80 B)
    __shared__ int activeF[8];

    const int bid = blockIdx.x;
    const int vid = (bid & 7) * 128 + (bid >> 3); // XCD-aware swizzle (1024 wgs, 8 XCDs);
                                                  // consecutive vids (same b,h,j) share an XCD -> K/V L2 reuse
    const int b = vid >> 9;
    const int h = (vid >> 5) & 15;
    const int j = (vid >> 2) & 7;
    const int qs = vid & 3;

    const int tid = threadIdx.x;
    const int w = tid >> 6;
    const int lane = tid & 63;
    const int l15 = lane & 15;
    const int g = lane >> 4;

    if (tid < 8) {
        // only the 4 layout rows this wg's 64 q-rows cover
        int a = 0;
        for (int r = 0; r < 4; ++r) a |= layout[(16 * j + 4 * qs + r) * 8 + tid];
        activeF[tid] = a;
    }

    const size_t bbase = (size_t)b * 2048 * 3072;
    const int qbase = 256 * j + 64 * qs + 16 * w;

    // Q fragments (B-operand of S^T): lane l -> Q[s = qbase+l15][d = kk*32+8g+e]
    f16x8 qf[2];
    {
        const float* qp = qkv + bbase + (size_t)(qbase + l15) * 3072 + h * 64;
        #pragma unroll
        for (int kk = 0; kk < 2; ++kk) {
            const float* p0 = qp + kk * 32 + 8 * g;
            float4 x = *(const float4*)p0;
            float4 y = *(const float4*)(p0 + 4);
            f16x8 q8;
            q8[0] = (_Float16)x.x; q8[1] = (_Float16)x.y; q8[2] = (_Float16)x.z; q8[3] = (_Float16)x.w;
            q8[4] = (_Float16)y.x; q8[5] = (_Float16)y.y; q8[6] = (_Float16)y.z; q8[7] = (_Float16)y.w;
            qf[kk] = q8;
        }
    }

    f32x4 acc[4]; // [dtile]: O^T[d=16*mt2+4g+r][q=l15]
    #pragma unroll
    for (int i0 = 0; i0 < 4; ++i0) acc[i0] = (f32x4){0.f, 0.f, 0.f, 0.f};
    float mrow = -INFINITY;
    float lrow = 0.f;

    __syncthreads();

    for (int kb = 0; kb < 8; ++kb) {
        if (!activeF[kb]) continue;
        for (int half = 0; half < 2; ++half) {
            __syncthreads();
            const size_t sbase = bbase + (size_t)(kb * 256 + half * 128) * 3072;
            // ---- stage K half-block: [key 0..127][d 0..63] f16, swizzled
            const float* kp0 = qkv + sbase + (16 + h) * 64;
            #pragma unroll 2
            for (int p = 0; p < 8; ++p) {
                int i = p * 256 + tid;
                int key = i >> 4, dc = i & 15;
                float4 v4 = *(const float4*)(kp0 + (size_t)key * 3072 + dc * 4);
                unsigned w0 = pk2(v4.x, v4.y), w1 = pk2(v4.z, v4.w);
                int off = (key * 128 + dc * 8) ^ ((key & 7) << 4);
                *(uint2*)((char*)Klds + off) = make_uint2(w0, w1);
            }
            // ---- stage V^T half-block: [d 0..63][key 0..127] f16, packed key-pairs
            const float* vp0 = qkv + sbase + (32 + h) * 64;
            #pragma unroll 2
            for (int p = 0; p < 4; ++p) {
                int i = p * 256 + tid;
                int kp = i >> 4, dc = i & 15; // keys 2kp,2kp+1; d = 4dc..4dc+3
                const float* r0 = vp0 + (size_t)(2 * kp) * 3072 + dc * 4;
                float4 va = *(const float4*)r0;
                float4 vb = *(const float4*)(r0 + 3072);
                #pragma unroll
                for (int e = 0; e < 4; ++e) {
                    int d = 4 * dc + e;
                    unsigned u = pk2((&va.x)[e], (&vb.x)[e]);
                    int off = (d * 256 + kp * 4) ^ (((d ^ (d >> 3)) & 7) << 4);
                    *(unsigned*)((char*)Vtlds + off) = u;
                }
            }
            __syncthreads();

            // ---- 4 chunks of 32 keys
            for (int c = 0; c < 4; ++c) {
                f16x8 kf[2][2];
                #pragma unroll
                for (int mt = 0; mt < 2; ++mt)
                    #pragma unroll
                    for (int kk = 0; kk < 2; ++kk) {
                        int key = c * 32 + 16 * mt + l15;
                        int off = (key * 128 + kk * 64 + g * 16) ^ ((key & 7) << 4);
                        kf[mt][kk] = *(const f16x8*)((const char*)Klds + off);
                    }
                f16x8 vf[4];
                #pragma unroll
                for (int mt = 0; mt < 4; ++mt) {
                    int d = 16 * mt + l15;
                    int off = (d * 256 + c * 64 + g * 16) ^ (((d ^ (d >> 3)) & 7) << 4);
                    vf[mt] = *(const f16x8*)((const char*)Vtlds + off);
                }
                // S^T tiles: lane holds S^T[key = c*32 + 16mt + 4g + r][q = l15]
                f32x4 st0 = {0.f, 0.f, 0.f, 0.f};
                f32x4 st1 = {0.f, 0.f, 0.f, 0.f};
                st0 = MFMA16(kf[0][0], qf[0], st0);
                st0 = MFMA16(kf[0][1], qf[1], st0);
                st1 = MFMA16(kf[1][0], qf[0], st1);
                st1 = MFMA16(kf[1][1], qf[1], st1);
                float s0[4], s1[4];
                float cm = -INFINITY;
                #pragma unroll
                for (int r = 0; r < 4; ++r) {
                    s0[r] = st0[r] * 0.125f;
                    s1[r] = st1[r] * 0.125f;
                    cm = fmaxf(cm, fmaxf(s0[r], s1[r]));
                }
                cm = fmaxf(cm, __shfl_xor(cm, 16));
                cm = fmaxf(cm, __shfl_xor(cm, 32));
                // exact defer-rescale: if no row's max grew, rs == 1 -> skip the O-pass
                bool grow = !__all(cm <= mrow);
                float mnew = fmaxf(mrow, cm);
                float rs = __expf(mrow - mnew);
                mrow = mnew;
                float p0[4], p1[4], ps = 0.f;
                #pragma unroll
                for (int r = 0; r < 4; ++r) {
                    p0[r] = __expf(s0[r] - mnew);
                    p1[r] = __expf(s1[r] - mnew);
                    ps += p0[r] + p1[r];
                }
                ps += __shfl_xor(ps, 16);
                ps += __shfl_xor(ps, 32);
                if (grow) {
                    lrow *= rs;
                    #pragma unroll
                    for (int mt2 = 0; mt2 < 4; ++mt2) {
                        acc[mt2][0] *= rs; acc[mt2][1] *= rs;
                        acc[mt2][2] *= rs; acc[mt2][3] *= rs;
                    }
                }
                lrow += ps;
                // P^T regs are 4 contiguous k of P[q][k] -> one b64 write per tile
                char* pb = (char*)(&Plds[w][0]) + l15 * 80;
                *(uint2*)(pb + 8 * g)      = make_uint2(pk2(p0[0], p0[1]), pk2(p0[2], p0[3]));
                *(uint2*)(pb + 32 + 8 * g) = make_uint2(pk2(p1[0], p1[1]), pk2(p1[2], p1[3]));
                // B-frag of P^T: row q = l15, k = 8g..8g+7 contiguous
                f16x8 pf = *(const f16x8*)((const char*)(&Plds[w][0]) + l15 * 80 + 16 * g);
                #pragma unroll
                for (int mt2 = 0; mt2 < 4; ++mt2)
                    acc[mt2] = MFMA16(vf[mt2], pf, acc[mt2]);
            }
        }
    }

    // epilogue: O = O^T / l ; lane's 4 regs are contiguous d -> float4 store
    {
        float inv = 1.0f / lrow;
        float* op = out + (((size_t)b * 2048 + (qbase + l15)) * 16 + h) * 64;
        #pragma unroll
        for (int mt2 = 0; mt2 < 4; ++mt2) {
            float4 o;
            o.x = acc[mt2][0] * inv;
            o.y = acc[mt2][1] * inv;
            o.z = acc[mt2][2] * inv;
            o.w = acc[mt2][3] * inv;
            *(float4*)(op + 16 * mt2 + 4 * g) = o;
        }
    }
}

extern "C" void kernel_launch(void* const* d_in, const int* in_sizes, int n_in,
                              void* d_out, int out_size, void* d_ws, size_t ws_size,
                              hipStream_t stream) {
    const float* qkv = (const float*)d_in[0];
    const int* layout = (const int*)d_in[1];
    float* out = (float*)d_out;
    fba_fwd<<<dim3(1024), dim3(256), 0, stream>>>(qkv, layout, out);
}